// Round 4
// baseline (3940.860 us; speedup 1.0000x reference)
//
#include <hip/hip_runtime.h>

#define BB 32
#define TT 400
#define HH 512
#define NSTEP 100
#define VO 511
#define LSEQ 101
#define NBLK 256
#define NTHR 512
#define AOFF (BB*NSTEP*VO)
#define AG __HIP_MEMORY_SCOPE_AGENT

typedef float f4 __attribute__((ext_vector_type(4)));

struct P {
  const float* x; const int* y; const float* emb;
  const float* wih; const float* whh; const float* bih; const float* bhh;
  const float* cw; const float* cb; const float* aw; const float* ab;
  const float* fw; const float* fb;
  float* out; int* ctrl; float* fws;
};

__device__ __forceinline__ float wredsum(float v) {
#pragma unroll
  for (int d = 1; d < 64; d <<= 1) v += __shfl_xor(v, d, 64);
  return v;
}

__device__ __forceinline__ void dot4f(float& acc, f4 wv, f4 av) {
  acc = fmaf(wv.x, av.x, fmaf(wv.y, av.y, fmaf(wv.z, av.z, fmaf(wv.w, av.w, acc))));
}

// cross-block communication: relaxed agent-scope atomics (cache-bypass,
// coherent at IC) — avoids agent fences (L2 writeback/invalidate) entirely.
__device__ __forceinline__ float gld(const float* q) {
  return __hip_atomic_load(q, __ATOMIC_RELAXED, AG);
}
__device__ __forceinline__ void gst(float* q, float v) {
  __hip_atomic_store(q, v, __ATOMIC_RELAXED, AG);
}

__global__ __launch_bounds__(NTHR, 2) void seq2seq_kernel(P p) {
  const int tid  = threadIdx.x;
  const int lane = tid & 63;
  const int wave = tid >> 6;
  const int blk  = blockIdx.x;
  // score-phase ids: 32 b * 8 t-chunks
  const int sb  = blk >> 3;
  const int tch = blk & 7;
  const int t0  = tch * 50;
  // gru/fc ids: 4 b-tiles(8b) * 64 h-slices
  const int btile = blk >> 6;
  const int hblk  = blk & 63;
  const int bbase = btile * 8;
  const int hg    = hblk * 8 + wave;   // gru output h, also fc row v
  const int h0s   = lane * 8;

  // ---- unioned LDS arena (score phase vs gru/fc phase, separated by gbar) ----
  __shared__ __align__(16) float smem[12288];   // 48 KB
  float* axs  = smem;               // [68]          (score)
  float* accS = smem + 128;         // [8][512]      (score)
  float* mS   = smem + 128 + 4096;  // [8]           (score)
  float* lS   = mS + 8;             // [8]           (score)
  float* Avec = smem;               // [8][1024]     (phase3)
  float* Bvec = smem + 8192;        // [8][512]      (phase3)
  __shared__ int combf;

  float* hxg  = p.fws;                  // [2][BB][HH] double buffer
  float* sxg  = hxg + 2*BB*HH;          // [BB][HH]
  float* axb  = sxg + BB*HH;            // [BB][TT]
  float* scg  = axb + BB*TT;            // [BB][TT]
  float* pm   = scg + BB*TT;            // [BB][8]
  float* pl   = pm  + 256;              // [BB][8]
  float* pacc = pl  + 256;              // [BB][8][HH]

  int* leafc = p.ctrl;                  // leaf i at [64*i]
  int* rootc = p.ctrl + 576;
  int* genc  = p.ctrl + 640;
  int* arrv  = p.ctrl + 704;            // arrival[b] at [704+16*b]

  // ---- persistent per-lane conv/attn weights (fp32, 8 h x 15 taps) ----
  float cwr[120];
  float cbr[8], awr[8];
#pragma unroll
  for (int j = 0; j < 8; ++j) {
    int h = h0s + j;
    cbr[j] = p.cb[h];
    awr[j] = p.aw[h];
#pragma unroll
    for (int k = 0; k < 15; ++k) cwr[j*15+k] = p.cw[h*15 + k];
  }
  const float atb = p.ab[0];

  // ---- persistent x cache: this thread's slice of x for all 100 steps ----
  // t-iters: t = t0 + wave + it*8, it in [0,7); valid while wave + it*8 < 50
  // (waves 0-1: 7 iters, waves 2-7: 6 iters). 8 h per iter -> <=56 VGPRs.
  float xreg[7][8];
#pragma unroll
  for (int it = 0; it < 7; ++it) {
    const bool valid = (it < 6) || (wave < 2);
    if (valid) {
      const int t = t0 + wave + it*8;
      const float* xp = p.x + ((size_t)sb*TT + t)*HH + h0s;
      f4 x0 = ((const f4*)xp)[0], x1 = ((const f4*)xp)[1];
      xreg[it][0]=x0.x; xreg[it][1]=x0.y; xreg[it][2]=x0.z; xreg[it][3]=x0.w;
      xreg[it][4]=x1.x; xreg[it][5]=x1.y; xreg[it][6]=x1.z; xreg[it][7]=x1.w;
    } else {
#pragma unroll
      for (int j = 0; j < 8; ++j) xreg[it][j] = 0.f;
    }
  }

  // ---- hierarchical global barrier (no agent fences; see R2 notes) ----
  auto gbar = [&]() {
    __syncthreads();
    if (tid == 0) {
      __builtin_amdgcn_s_waitcnt(0);
      unsigned g = __hip_atomic_load((unsigned*)genc, __ATOMIC_RELAXED, AG);
      int li = blk & 7;
      if (__hip_atomic_fetch_add((unsigned*)&leafc[li*64], 1u, __ATOMIC_RELAXED, AG) == 31u) {
        __hip_atomic_store((unsigned*)&leafc[li*64], 0u, __ATOMIC_RELAXED, AG);
        if (__hip_atomic_fetch_add((unsigned*)rootc, 1u, __ATOMIC_RELAXED, AG) == 7u) {
          __hip_atomic_store((unsigned*)rootc, 0u, __ATOMIC_RELAXED, AG);
          __hip_atomic_fetch_add((unsigned*)genc, 1u, __ATOMIC_RELAXED, AG);
        }
      }
      while (__hip_atomic_load((unsigned*)genc, __ATOMIC_RELAXED, AG) == g)
        __builtin_amdgcn_s_sleep(2);
    }
    __syncthreads();
  };

  // ---- phase3(s): FC for step s (if s>=0) + GRU producing hx_{s+1} (if s<99) ----
  auto phase3 = [&](int s) {
    const bool dofc  = (s >= 0);
    const bool dogru = (s < NSTEP - 1);
    const int u = s + 1;
    const int parNow = s & 1;
    const int parNxt = u & 1;
#pragma unroll 1
    for (int b8 = 0; b8 < 8; ++b8) {
      const int b = bbase + b8;
      const int c = tid;
      float hxv = 0.f, sxv = 0.f;
      if (dofc) {
        hxv = gld(&hxg[parNow*BB*HH + b*HH + c]);
        sxv = gld(&sxg[b*HH + c]);
        Bvec[b8*512 + c] = hxv + sxv;
      }
      if (dogru) {
        const int yb = p.y[b*LSEQ + u];
        Avec[b8*1024 + c]       = p.emb[yb*HH + c] + sxv;
        Avec[b8*1024 + 512 + c] = hxv;
      }
    }
    __syncthreads();
    if (dofc && hg < VO) {
      const float* fr = p.fw + (size_t)hg*HH + h0s;
      f4 fw0 = ((const f4*)fr)[0], fw1 = ((const f4*)fr)[1];
      float fbv = p.fb[hg];
#pragma unroll 1
      for (int b8 = 0; b8 < 8; ++b8) {
        const f4* bp = (const f4*)(&Bvec[b8*512 + h0s]);
        f4 b0 = bp[0], b1 = bp[1];
        float d = 0.f;
        dot4f(d, fw0, b0); dot4f(d, fw1, b1);
        d = wredsum(d);
        if (lane == 0)
          p.out[(size_t)(bbase+b8)*NSTEP*VO + (size_t)s*VO + hg] = d + fbv;
      }
    }
    if (dogru) {
      const int half = lane >> 5;
      const int lk = (lane & 31) * 16;
      const float* base1 = (half ? p.whh : p.wih);
      const float* w1p = base1 + (size_t)hg*HH + lk;
      const float* w2p = base1 + (size_t)(512+hg)*HH + lk;
      const float* w3p = base1 + (size_t)(1024+hg)*HH + lk;
      f4 wr_[4], wz_[4], wn_[4];
#pragma unroll
      for (int q = 0; q < 4; ++q) {
        wr_[q] = ((const f4*)w1p)[q];
        wz_[q] = ((const f4*)w2p)[q];
        wn_[q] = ((const f4*)w3p)[q];
      }
      const float br  = p.bih[hg] + p.bhh[hg];
      const float bz  = p.bih[512+hg] + p.bhh[512+hg];
      const float bin = p.bih[1024+hg];
      const float bhn = p.bhh[1024+hg];
#pragma unroll 1
      for (int b8 = 0; b8 < 8; ++b8) {
        const f4* ap = (const f4*)(&Avec[b8*1024 + lane*16]);
        f4 a0 = ap[0], a1 = ap[1], a2 = ap[2], a3 = ap[3];
        float d1 = 0.f, d2 = 0.f, d3 = 0.f;
        dot4f(d1, wr_[0], a0); dot4f(d1, wr_[1], a1); dot4f(d1, wr_[2], a2); dot4f(d1, wr_[3], a3);
        dot4f(d2, wz_[0], a0); dot4f(d2, wz_[1], a1); dot4f(d2, wz_[2], a2); dot4f(d2, wz_[3], a3);
        dot4f(d3, wn_[0], a0); dot4f(d3, wn_[1], a1); dot4f(d3, wn_[2], a2); dot4f(d3, wn_[3], a3);
#pragma unroll
        for (int dd = 1; dd <= 32; dd <<= 1) { d1 += __shfl_xor(d1, dd, 64); d2 += __shfl_xor(d2, dd, 64); }
#pragma unroll
        for (int dd = 1; dd <= 16; dd <<= 1) d3 += __shfl_xor(d3, dd, 64);
        float d3o = __shfl_xor(d3, 32, 64);
        float i_n = half ? d3o : d3;
        float h_n = half ? d3  : d3o;
        float rg = 1.f / (1.f + __expf(-(d1 + br)));
        float zg = 1.f / (1.f + __expf(-(d2 + bz)));
        float na = (i_n + bin) + rg * (h_n + bhn);
        float e2 = __expf(2.f * na);
        float nn = 1.f - 2.f / (e2 + 1.f);
        float hold = Avec[b8*1024 + 512 + hg];
        float hnew = (1.f - zg) * nn + zg * hold;
        if (lane == 0) gst(&hxg[parNxt*BB*HH + (bbase+b8)*HH + hg], hnew);
      }
    }
  };

  // ---- score phase for step s: conv + relu-dot + flash softmax-weighted sum ----
  auto score = [&](int s) {
    const int par = s & 1;
    if (s > 0) {
      if (tid < 68) {
        int tg = t0 - 8 + tid;
        axs[tid] = (tg >= 0 && tg < TT) ? gld(&axb[sb*TT + tg]) : 0.f;
      }
      __syncthreads();
    }
    const float* hxp = hxg + par*BB*HH + sb*HH + h0s;
    float hxr[8];
#pragma unroll
    for (int j = 0; j < 8; ++j) hxr[j] = gld(hxp + j);
    float m = -1e30f, l = 0.f;
    float acc[8];
#pragma unroll
    for (int j = 0; j < 8; ++j) acc[j] = 0.f;
#pragma unroll
    for (int it = 0; it < 7; ++it) {
      const bool valid = (it < 6) || (wave < 2);
      if (valid) {
        const int t = t0 + wave + it*8;
        float cc[8];
        if (s > 0) {
          // ax[t-7+k] lives at axs[(t - t0 + 1) + k]
          const int li0 = wave + it*8 + 1;
          float axv[15];
#pragma unroll
          for (int k = 0; k < 15; ++k) axv[k] = axs[li0 + k];
#pragma unroll
          for (int j = 0; j < 8; ++j) {
            float a = cbr[j];
#pragma unroll
            for (int k = 0; k < 15; ++k) a = fmaf(cwr[j*15+k], axv[k], a);
            cc[j] = a;
          }
        } else {
#pragma unroll
          for (int j = 0; j < 8; ++j) cc[j] = 0.f;
        }
        float part = 0.f;
#pragma unroll
        for (int j = 0; j < 8; ++j) {
          float vv = xreg[it][j] + hxr[j] + cc[j];
          vv = fmaxf(vv, 0.f);
          part = fmaf(vv, awr[j], part);
        }
        part = wredsum(part);
        float st = part + atb;
        if (lane == 0) gst(&scg[sb*TT + t], st);
        float mn  = fmaxf(m, st);
        float scl = __expf(m - mn);
        float pe  = __expf(st - mn);
        l = l * scl + pe;
#pragma unroll
        for (int j = 0; j < 8; ++j) acc[j] = fmaf(acc[j], scl, pe * xreg[it][j]);
        m = mn;
      }
    }
    {
      f4 s0 = {acc[0],acc[1],acc[2],acc[3]}, s1_ = {acc[4],acc[5],acc[6],acc[7]};
      ((f4*)(&accS[wave*512 + h0s]))[0] = s0;
      ((f4*)(&accS[wave*512 + h0s]))[1] = s1_;
      if (lane == 0) { mS[wave] = m; lS[wave] = l; }
    }
    __syncthreads();
    float mb = mS[0];
#pragma unroll
    for (int w = 1; w < 8; ++w) mb = fmaxf(mb, mS[w]);
    float lb = 0.f, ew[8];
#pragma unroll
    for (int w = 0; w < 8; ++w) { ew[w] = __expf(mS[w] - mb); lb = fmaf(ew[w], lS[w], lb); }
    float ab_ = 0.f;
#pragma unroll
    for (int w = 0; w < 8; ++w) ab_ = fmaf(ew[w], accS[w*512 + tid], ab_);
    gst(&pacc[(size_t)(sb*8 + tch)*HH + tid], ab_);
    if (tid == 0) { gst(&pm[sb*8+tch], mb); gst(&pl[sb*8+tch], lb); }
    __syncthreads();
    if (tid == 0) {
      __builtin_amdgcn_s_waitcnt(0);
      unsigned old = __hip_atomic_fetch_add((unsigned*)&arrv[16*sb], 1u, __ATOMIC_RELAXED, AG);
      combf = (old == 7u) ? 1 : 0;
    }
    __syncthreads();
    if (combf) {
      if (tid == 0) __hip_atomic_store((unsigned*)&arrv[16*sb], 0u, __ATOMIC_RELAXED, AG);
      float pmv[8], plv[8];
#pragma unroll
      for (int c = 0; c < 8; ++c) { pmv[c] = gld(&pm[sb*8+c]); plv[c] = gld(&pl[sb*8+c]); }
      float mm2 = pmv[0];
#pragma unroll
      for (int c = 1; c < 8; ++c) mm2 = fmaxf(mm2, pmv[c]);
      float ls = 0.f, ee[8];
#pragma unroll
      for (int c = 0; c < 8; ++c) { ee[c] = __expf(pmv[c] - mm2); ls = fmaf(ee[c], plv[c], ls); }
      float inv = 1.f / ls;
      float sv = 0.f;
#pragma unroll
      for (int c = 0; c < 8; ++c) sv = fmaf(ee[c], gld(&pacc[(size_t)(sb*8+c)*HH + tid]), sv);
      gst(&sxg[sb*HH + tid], sv * inv);
      for (int t = tid; t < TT; t += NTHR) {
        float a = __expf(gld(&scg[sb*TT + t]) - mm2) * inv;
        gst(&axb[sb*TT + t], a);
        p.out[AOFF + (size_t)sb*NSTEP*TT + (size_t)s*TT + t] = a;
      }
    }
  };

  // ---- main sequence ----
  phase3(-1);          // GRU step 0 (hx=0, sx=0)
  gbar();
  for (int s = 0; s < NSTEP; ++s) {
    score(s);
    gbar();
    phase3(s);
    gbar();
  }
}

extern "C" void kernel_launch(void* const* d_in, const int* in_sizes, int n_in,
                              void* d_out, int out_size, void* d_ws, size_t ws_size,
                              hipStream_t stream) {
  P p;
  p.x   = (const float*)d_in[0];
  p.y   = (const int*)  d_in[1];
  p.emb = (const float*)d_in[2];
  p.wih = (const float*)d_in[3];
  p.whh = (const float*)d_in[4];
  p.bih = (const float*)d_in[5];
  p.bhh = (const float*)d_in[6];
  p.cw  = (const float*)d_in[7];
  p.cb  = (const float*)d_in[8];
  p.aw  = (const float*)d_in[9];
  p.ab  = (const float*)d_in[10];
  p.fw  = (const float*)d_in[11];
  p.fb  = (const float*)d_in[12];
  p.out = (float*)d_out;
  p.ctrl = (int*)d_ws;
  p.fws  = (float*)d_ws + 4096;

  // zero barrier/ticket control region (d_ws is poisoned before every launch)
  hipMemsetAsync(d_ws, 0, 16384, stream);

  void* args[] = { &p };
  hipError_t err = hipLaunchCooperativeKernel((const void*)seq2seq_kernel,
                                              dim3(NBLK), dim3(NTHR), args, 0, stream);
  if (err != hipSuccess) {
    // fallback: plain launch (256 blocks, 1 block/CU => co-resident in practice)
    seq2seq_kernel<<<dim3(NBLK), dim3(NTHR), 0, stream>>>(p);
  }
}

// Round 5
// 3162.442 us; speedup vs baseline: 1.2461x; 1.2461x over previous
//
#include <hip/hip_runtime.h>

#define BB 32
#define TT 400
#define HH 512
#define NSTEP 100
#define VO 511
#define LSEQ 101
#define NBLK 256
#define NTHR 512
#define AOFF (BB*NSTEP*VO)
#define AG __HIP_MEMORY_SCOPE_AGENT

typedef float f4 __attribute__((ext_vector_type(4)));
typedef _Float16 hf8 __attribute__((ext_vector_type(8)));

struct P {
  const float* x; const int* y; const float* emb;
  const float* wih; const float* whh; const float* bih; const float* bhh;
  const float* cw; const float* cb; const float* aw; const float* ab;
  const float* fw; const float* fb;
  float* out; int* ctrl; float* fws; _Float16* xh;
};

__device__ __forceinline__ float wredsum(float v) {
#pragma unroll
  for (int d = 1; d < 64; d <<= 1) v += __shfl_xor(v, d, 64);
  return v;
}

__device__ __forceinline__ void dot4f(float& acc, f4 wv, f4 av) {
  acc = fmaf(wv.x, av.x, fmaf(wv.y, av.y, fmaf(wv.z, av.z, fmaf(wv.w, av.w, acc))));
}

// cross-block communication: relaxed agent-scope atomics (cache-bypass,
// coherent at IC) — avoids agent fences (L2 writeback/invalidate) entirely.
__device__ __forceinline__ float gld(const float* q) {
  return __hip_atomic_load(q, __ATOMIC_RELAXED, AG);
}
__device__ __forceinline__ void gst(float* q, float v) {
  __hip_atomic_store(q, v, __ATOMIC_RELAXED, AG);
}

__global__ __launch_bounds__(NTHR, 2) void seq2seq_kernel(P p) {
  const int tid  = threadIdx.x;
  const int lane = tid & 63;
  const int wave = tid >> 6;
  const int blk  = blockIdx.x;
  // score-phase ids: 32 b * 8 t-chunks
  const int sb  = blk >> 3;
  const int tch = blk & 7;
  const int t0  = tch * 50;
  // gru/fc ids: 4 b-tiles(8b) * 64 h-slices
  const int btile = blk >> 6;
  const int hblk  = blk & 63;
  const int bbase = btile * 8;
  const int hg    = hblk * 8 + wave;   // gru output h, also fc row v
  const int h0s   = lane * 8;

  // ---- unioned LDS arena (score phase vs gru/fc phase, separated by gbar) ----
  __shared__ __align__(16) float smem[12288];   // 48 KB
  float* axs  = smem;               // [68]          (score)
  float* accS = smem + 128;         // [8][512]      (score)
  float* mS   = smem + 128 + 4096;  // [8]           (score)
  float* lS   = mS + 8;             // [8]           (score)
  float* Avec = smem;               // [8][1024]     (phase3)
  float* Bvec = smem + 8192;        // [8][512]      (phase3)
  __shared__ int combf;

  float* hxg  = p.fws;                  // [2][BB][HH] double buffer
  float* sxg  = hxg + 2*BB*HH;          // [BB][HH]
  float* axb  = sxg + BB*HH;            // [BB][TT]
  float* scg  = axb + BB*TT;            // [BB][TT]
  float* pm   = scg + BB*TT;            // [BB][8]
  float* pl   = pm  + 256;              // [BB][8]
  float* pacc = pl  + 256;              // [BB][8][HH]

  int* leafc = p.ctrl;                  // leaf i at [64*i]
  int* rootc = p.ctrl + 576;
  int* genc  = p.ctrl + 640;
  int* arrv  = p.ctrl + 704;            // arrival[b] at [704+16*b]

  // ---- persistent per-lane conv/attn weights (fp32, 8 h x 15 taps; lives in
  //      unified VGPR+AGPR file at 2 waves/SIMD — do NOT add more big arrays) ----
  float cwr[120];
  float cbr[8], awr[8];
#pragma unroll
  for (int j = 0; j < 8; ++j) {
    int h = h0s + j;
    cbr[j] = p.cb[h];
    awr[j] = p.aw[h];
#pragma unroll
    for (int k = 0; k < 15; ++k) cwr[j*15+k] = p.cw[h*15 + k];
  }
  const float atb = p.ab[0];

  // ---- one-time: convert this block's private x-slice to fp16 in d_ws.
  //      Halves the steady-state footprint: per-XCD working set ~2.7 MB < 4 MB
  //      L2 -> x reads become L2 hits for all 100 steps (R3 thrashed at 4.3 MB).
  //      Written and read by the SAME thread; __syncthreads drains vmcnt. ----
  {
#pragma unroll
    for (int it = 0; it < 7; ++it) {
      const bool valid = (it < 6) || (wave < 2);
      if (valid) {
        const int t = t0 + wave + it*8;
        const float* xp = p.x + ((size_t)sb*TT + t)*HH + h0s;
        f4 x0 = ((const f4*)xp)[0], x1 = ((const f4*)xp)[1];
        hf8 xv;
        xv[0]=(_Float16)x0.x; xv[1]=(_Float16)x0.y; xv[2]=(_Float16)x0.z; xv[3]=(_Float16)x0.w;
        xv[4]=(_Float16)x1.x; xv[5]=(_Float16)x1.y; xv[6]=(_Float16)x1.z; xv[7]=(_Float16)x1.w;
        *(hf8*)(p.xh + ((size_t)sb*TT + t)*HH + h0s) = xv;
      }
    }
    __syncthreads();
  }

  // ---- hierarchical global barrier (no agent fences; see R2 notes) ----
  auto gbar = [&]() {
    __syncthreads();
    if (tid == 0) {
      __builtin_amdgcn_s_waitcnt(0);
      unsigned g = __hip_atomic_load((unsigned*)genc, __ATOMIC_RELAXED, AG);
      int li = blk & 7;
      if (__hip_atomic_fetch_add((unsigned*)&leafc[li*64], 1u, __ATOMIC_RELAXED, AG) == 31u) {
        __hip_atomic_store((unsigned*)&leafc[li*64], 0u, __ATOMIC_RELAXED, AG);
        if (__hip_atomic_fetch_add((unsigned*)rootc, 1u, __ATOMIC_RELAXED, AG) == 7u) {
          __hip_atomic_store((unsigned*)rootc, 0u, __ATOMIC_RELAXED, AG);
          __hip_atomic_fetch_add((unsigned*)genc, 1u, __ATOMIC_RELAXED, AG);
        }
      }
      while (__hip_atomic_load((unsigned*)genc, __ATOMIC_RELAXED, AG) == g)
        __builtin_amdgcn_s_sleep(2);
    }
    __syncthreads();
  };

  // ---- phase3(s): FC for step s (if s>=0) + GRU producing hx_{s+1} (if s<99) ----
  auto phase3 = [&](int s) {
    const bool dofc  = (s >= 0);
    const bool dogru = (s < NSTEP - 1);
    const int u = s + 1;
    const int parNow = s & 1;
    const int parNxt = u & 1;
#pragma unroll 1
    for (int b8 = 0; b8 < 8; ++b8) {
      const int b = bbase + b8;
      const int c = tid;
      float hxv = 0.f, sxv = 0.f;
      if (dofc) {
        hxv = gld(&hxg[parNow*BB*HH + b*HH + c]);
        sxv = gld(&sxg[b*HH + c]);
        Bvec[b8*512 + c] = hxv + sxv;
      }
      if (dogru) {
        const int yb = p.y[b*LSEQ + u];
        Avec[b8*1024 + c]       = p.emb[yb*HH + c] + sxv;
        Avec[b8*1024 + 512 + c] = hxv;
      }
    }
    __syncthreads();
    if (dofc && hg < VO) {
      const float* fr = p.fw + (size_t)hg*HH + h0s;
      f4 fw0 = ((const f4*)fr)[0], fw1 = ((const f4*)fr)[1];
      float fbv = p.fb[hg];
#pragma unroll 1
      for (int b8 = 0; b8 < 8; ++b8) {
        const f4* bp = (const f4*)(&Bvec[b8*512 + h0s]);
        f4 b0 = bp[0], b1 = bp[1];
        float d = 0.f;
        dot4f(d, fw0, b0); dot4f(d, fw1, b1);
        d = wredsum(d);
        if (lane == 0)
          p.out[(size_t)(bbase+b8)*NSTEP*VO + (size_t)s*VO + hg] = d + fbv;
      }
    }
    if (dogru) {
      const int half = lane >> 5;
      const int lk = (lane & 31) * 16;
      const float* base1 = (half ? p.whh : p.wih);
      const float* w1p = base1 + (size_t)hg*HH + lk;
      const float* w2p = base1 + (size_t)(512+hg)*HH + lk;
      const float* w3p = base1 + (size_t)(1024+hg)*HH + lk;
      f4 wr_[4], wz_[4], wn_[4];
#pragma unroll
      for (int q = 0; q < 4; ++q) {
        wr_[q] = ((const f4*)w1p)[q];
        wz_[q] = ((const f4*)w2p)[q];
        wn_[q] = ((const f4*)w3p)[q];
      }
      const float br  = p.bih[hg] + p.bhh[hg];
      const float bz  = p.bih[512+hg] + p.bhh[512+hg];
      const float bin = p.bih[1024+hg];
      const float bhn = p.bhh[1024+hg];
#pragma unroll 1
      for (int b8 = 0; b8 < 8; ++b8) {
        const f4* ap = (const f4*)(&Avec[b8*1024 + lane*16]);
        f4 a0 = ap[0], a1 = ap[1], a2 = ap[2], a3 = ap[3];
        float d1 = 0.f, d2 = 0.f, d3 = 0.f;
        dot4f(d1, wr_[0], a0); dot4f(d1, wr_[1], a1); dot4f(d1, wr_[2], a2); dot4f(d1, wr_[3], a3);
        dot4f(d2, wz_[0], a0); dot4f(d2, wz_[1], a1); dot4f(d2, wz_[2], a2); dot4f(d2, wz_[3], a3);
        dot4f(d3, wn_[0], a0); dot4f(d3, wn_[1], a1); dot4f(d3, wn_[2], a2); dot4f(d3, wn_[3], a3);
#pragma unroll
        for (int dd = 1; dd <= 32; dd <<= 1) { d1 += __shfl_xor(d1, dd, 64); d2 += __shfl_xor(d2, dd, 64); }
#pragma unroll
        for (int dd = 1; dd <= 16; dd <<= 1) d3 += __shfl_xor(d3, dd, 64);
        float d3o = __shfl_xor(d3, 32, 64);
        float i_n = half ? d3o : d3;
        float h_n = half ? d3  : d3o;
        float rg = 1.f / (1.f + __expf(-(d1 + br)));
        float zg = 1.f / (1.f + __expf(-(d2 + bz)));
        float na = (i_n + bin) + rg * (h_n + bhn);
        float e2 = __expf(2.f * na);
        float nn = 1.f - 2.f / (e2 + 1.f);
        float hold = Avec[b8*1024 + 512 + hg];
        float hnew = (1.f - zg) * nn + zg * hold;
        if (lane == 0) gst(&hxg[parNxt*BB*HH + (bbase+b8)*HH + hg], hnew);
      }
    }
  };

  // ---- score phase for step s: conv + relu-dot + flash softmax-weighted sum ----
  auto score = [&](int s) {
    const int par = s & 1;
    if (s > 0) {
      if (tid < 68) {
        int tg = t0 - 8 + tid;
        axs[tid] = (tg >= 0 && tg < TT) ? gld(&axb[sb*TT + tg]) : 0.f;
      }
      __syncthreads();
    }
    const float* hxp = hxg + par*BB*HH + sb*HH + h0s;
    float hxr[8];
#pragma unroll
    for (int j = 0; j < 8; ++j) hxr[j] = gld(hxp + j);
    float m = -1e30f, l = 0.f;
    float acc[8];
#pragma unroll
    for (int j = 0; j < 8; ++j) acc[j] = 0.f;
#pragma unroll 1
    for (int t = t0 + wave; t < t0 + 50; t += 8) {
      hf8 xv = *(const hf8*)(p.xh + ((size_t)sb*TT + t)*HH + h0s);
      float xr[8];
#pragma unroll
      for (int j = 0; j < 8; ++j) xr[j] = (float)xv[j];
      float cc[8];
      if (s > 0) {
        // ax[t-7+k] lives at axs[(t - t0 + 1) + k]
        const int li0 = (t - t0) + 1;
        float axv[15];
#pragma unroll
        for (int k = 0; k < 15; ++k) axv[k] = axs[li0 + k];
#pragma unroll
        for (int j = 0; j < 8; ++j) {
          float a = cbr[j];
#pragma unroll
          for (int k = 0; k < 15; ++k) a = fmaf(cwr[j*15+k], axv[k], a);
          cc[j] = a;
        }
      } else {
#pragma unroll
        for (int j = 0; j < 8; ++j) cc[j] = 0.f;
      }
      float part = 0.f;
#pragma unroll
      for (int j = 0; j < 8; ++j) {
        float vv = xr[j] + hxr[j] + cc[j];
        vv = fmaxf(vv, 0.f);
        part = fmaf(vv, awr[j], part);
      }
      part = wredsum(part);
      float st = part + atb;
      if (lane == 0) gst(&scg[sb*TT + t], st);
      float mn  = fmaxf(m, st);
      float scl = __expf(m - mn);
      float pe  = __expf(st - mn);
      l = l * scl + pe;
#pragma unroll
      for (int j = 0; j < 8; ++j) acc[j] = fmaf(acc[j], scl, pe * xr[j]);
      m = mn;
    }
    {
      f4 s0 = {acc[0],acc[1],acc[2],acc[3]}, s1_ = {acc[4],acc[5],acc[6],acc[7]};
      ((f4*)(&accS[wave*512 + h0s]))[0] = s0;
      ((f4*)(&accS[wave*512 + h0s]))[1] = s1_;
      if (lane == 0) { mS[wave] = m; lS[wave] = l; }
    }
    __syncthreads();
    float mb = mS[0];
#pragma unroll
    for (int w = 1; w < 8; ++w) mb = fmaxf(mb, mS[w]);
    float lb = 0.f, ew[8];
#pragma unroll
    for (int w = 0; w < 8; ++w) { ew[w] = __expf(mS[w] - mb); lb = fmaf(ew[w], lS[w], lb); }
    float ab_ = 0.f;
#pragma unroll
    for (int w = 0; w < 8; ++w) ab_ = fmaf(ew[w], accS[w*512 + tid], ab_);
    gst(&pacc[(size_t)(sb*8 + tch)*HH + tid], ab_);
    if (tid == 0) { gst(&pm[sb*8+tch], mb); gst(&pl[sb*8+tch], lb); }
    __syncthreads();
    if (tid == 0) {
      __builtin_amdgcn_s_waitcnt(0);
      unsigned old = __hip_atomic_fetch_add((unsigned*)&arrv[16*sb], 1u, __ATOMIC_RELAXED, AG);
      combf = (old == 7u) ? 1 : 0;
    }
    __syncthreads();
    if (combf) {
      if (tid == 0) __hip_atomic_store((unsigned*)&arrv[16*sb], 0u, __ATOMIC_RELAXED, AG);
      float pmv[8], plv[8];
#pragma unroll
      for (int c = 0; c < 8; ++c) { pmv[c] = gld(&pm[sb*8+c]); plv[c] = gld(&pl[sb*8+c]); }
      float mm2 = pmv[0];
#pragma unroll
      for (int c = 1; c < 8; ++c) mm2 = fmaxf(mm2, pmv[c]);
      float ls = 0.f, ee[8];
#pragma unroll
      for (int c = 0; c < 8; ++c) { ee[c] = __expf(pmv[c] - mm2); ls = fmaf(ee[c], plv[c], ls); }
      float inv = 1.f / ls;
      float sv = 0.f;
#pragma unroll
      for (int c = 0; c < 8; ++c) sv = fmaf(ee[c], gld(&pacc[(size_t)(sb*8+c)*HH + tid]), sv);
      gst(&sxg[sb*HH + tid], sv * inv);
      for (int t = tid; t < TT; t += NTHR) {
        float a = __expf(gld(&scg[sb*TT + t]) - mm2) * inv;
        gst(&axb[sb*TT + t], a);
        p.out[AOFF + (size_t)sb*NSTEP*TT + (size_t)s*TT + t] = a;
      }
    }
  };

  // ---- main sequence ----
  phase3(-1);          // GRU step 0 (hx=0, sx=0)
  gbar();
  for (int s = 0; s < NSTEP; ++s) {
    score(s);
    gbar();
    phase3(s);
    gbar();
  }
}

extern "C" void kernel_launch(void* const* d_in, const int* in_sizes, int n_in,
                              void* d_out, int out_size, void* d_ws, size_t ws_size,
                              hipStream_t stream) {
  P p;
  p.x   = (const float*)d_in[0];
  p.y   = (const int*)  d_in[1];
  p.emb = (const float*)d_in[2];
  p.wih = (const float*)d_in[3];
  p.whh = (const float*)d_in[4];
  p.bih = (const float*)d_in[5];
  p.bhh = (const float*)d_in[6];
  p.cw  = (const float*)d_in[7];
  p.cb  = (const float*)d_in[8];
  p.aw  = (const float*)d_in[9];
  p.ab  = (const float*)d_in[10];
  p.fw  = (const float*)d_in[11];
  p.fb  = (const float*)d_in[12];
  p.out = (float*)d_out;
  p.ctrl = (int*)d_ws;                       // 16 KB control region
  p.fws  = (float*)d_ws + 4096;              // ~825 KB fp32 scratch
  p.xh   = (_Float16*)((char*)d_ws + 16384 + 1048576);  // 13.1 MB fp16 x-copy

  // zero barrier/ticket control region (d_ws is poisoned before every launch)
  hipMemsetAsync(d_ws, 0, 16384, stream);

  void* args[] = { &p };
  hipError_t err = hipLaunchCooperativeKernel((const void*)seq2seq_kernel,
                                              dim3(NBLK), dim3(NTHR), args, 0, stream);
  if (err != hipSuccess) {
    // fallback: plain launch (256 blocks, 1 block/CU => co-resident in practice)
    seq2seq_kernel<<<dim3(NBLK), dim3(NTHR), 0, stream>>>(p);
  }
}